// Round 2
// baseline (866.177 us; speedup 1.0000x reference)
//
#include <hip/hip_runtime.h>

#define NLVL 16
#define NFEAT 2

typedef float f32x2 __attribute__((ext_vector_type(2)));

// One thread per (point, level).
// tid = b*16 + l  -> 16 consecutive lanes share a point; wave covers 4 points.
// Output row per point = 32 floats = 128 B, written as coalesced 8B per lane.
__global__ __launch_bounds__(256) void hashgrid_encode_kernel(
    const float* __restrict__ xyz,
    const float* __restrict__ emb,
    const int*   __restrict__ offsets,
    const int*   __restrict__ resolutions,
    const float* __restrict__ min_xyz,
    const float* __restrict__ max_xyz,
    float* __restrict__ out,
    int B)
{
    int tid = blockIdx.x * blockDim.x + threadIdx.x;
    int b = tid >> 4;
    int l = tid & 15;
    if (b >= B) return;

    // --- bit-exact u computation (must match reference fp32 ops) ---
    float mn0 = min_xyz[0], mn1 = min_xyz[1], mn2 = min_xyz[2];
    float mx0 = max_xyz[0], mx1 = max_xyz[1], mx2 = max_xyz[2];
    float x = xyz[b * 3 + 0];
    float y = xyz[b * 3 + 1];
    float z = xyz[b * 3 + 2];
    float ux = (x - mn0) / (mx0 - mn0);
    float uy = (y - mn1) / (mx1 - mn1);
    float uz = (z - mn2) / (mx2 - mn2);
    bool valid = (ux >= 0.0f) & (ux <= 1.0f) &
                 (uy >= 0.0f) & (uy <= 1.0f) &
                 (uz >= 0.0f) & (uz <= 1.0f);

    float res = (float)resolutions[l];
    float rm1 = res - 1.0f;
    float px = ux * res, py = uy * res, pz = uz * res;
    float p0x = fminf(fmaxf(floorf(px), 0.0f), rm1);
    float p0y = fminf(fmaxf(floorf(py), 0.0f), rm1);
    float p0z = fminf(fmaxf(floorf(pz), 0.0f), rm1);
    float fx = px - p0x, fy = py - p0y, fz = pz - p0z;
    float gx = 1.0f - fx, gy = 1.0f - fy, gz = 1.0f - fz;

    unsigned cx0 = (unsigned)p0x;
    unsigned cy0 = (unsigned)p0y;
    unsigned cz0 = (unsigned)p0z;

    unsigned off  = (unsigned)offsets[l];
    unsigned size = (unsigned)offsets[l + 1] - off;
    unsigned mask = size - 1u;
    bool pow2 = (size & mask) == 0u;

    const unsigned P1 = 2654435761u;
    const unsigned P2 = 805459861u;

    float o0 = 0.0f, o1 = 0.0f;
#pragma unroll
    for (int c = 0; c < 8; ++c) {
        unsigned bx = (unsigned)(c & 1);
        unsigned by = (unsigned)((c >> 1) & 1);
        unsigned bz = (unsigned)((c >> 2) & 1);
        unsigned h = (cx0 + bx) ^ ((cy0 + by) * P1) ^ ((cz0 + bz) * P2);
        unsigned hm = pow2 ? (h & mask) : (h % size);
        unsigned idx = hm + off;
        // weight: prod over dims in order d0,d1,d2 (matches jnp.prod)
        float w = (bx ? fx : gx) * (by ? fy : gy);
        w = w * (bz ? fz : gz);
        const float2 g = *reinterpret_cast<const float2*>(emb + (size_t)idx * NFEAT);
        o0 += w * g.x;
        o1 += w * g.y;
    }
    if (!valid) { o0 = 0.0f; o1 = 0.0f; }

    f32x2 result;
    result.x = o0;
    result.y = o1;
    f32x2* op = reinterpret_cast<f32x2*>(out + (size_t)b * (NLVL * NFEAT) + l * NFEAT);
    __builtin_nontemporal_store(result, op);
}

extern "C" void kernel_launch(void* const* d_in, const int* in_sizes, int n_in,
                              void* d_out, int out_size, void* d_ws, size_t ws_size,
                              hipStream_t stream) {
    const float* xyz        = (const float*)d_in[0];
    const float* embeddings = (const float*)d_in[1];
    const int*   offsets    = (const int*)d_in[2];
    const int*   resolutions= (const int*)d_in[3];
    const float* min_xyz    = (const float*)d_in[4];
    const float* max_xyz    = (const float*)d_in[5];
    float* out = (float*)d_out;

    int B = in_sizes[0] / 3;
    int total = B * NLVL;
    int block = 256;
    int grid = (total + block - 1) / block;
    hashgrid_encode_kernel<<<grid, block, 0, stream>>>(
        xyz, embeddings, offsets, resolutions, min_xyz, max_xyz, out, B);
}

// Round 3
// 706.288 us; speedup vs baseline: 1.2264x; 1.2264x over previous
//
#include <hip/hip_runtime.h>

#define NLVL 16
#define NFEAT 2

typedef float f32x2 __attribute__((ext_vector_type(2)));

// One block = one level x 256 points. Level is wave-uniform (SGPR params).
// blockIdx.x % 16 selects the level via perm pairing (l, 15-l) so that
// XCD x (= blockIdx.x % 8, round-robin dispatch) sees only levels {x, 15-x}:
// one ~4MiB fine table + one small coarse table -> fits the XCD's 4 MiB L2.
__global__ __launch_bounds__(256) void hashgrid_encode_lvl_kernel(
    const float* __restrict__ xyz,
    const float* __restrict__ emb,
    const int*   __restrict__ offsets,
    const int*   __restrict__ resolutions,
    const float* __restrict__ min_xyz,
    const float* __restrict__ max_xyz,
    float* __restrict__ out,
    int B)
{
    int g = blockIdx.x & 15;
    int chunk = blockIdx.x >> 4;
    int l = (g < 8) ? g : (23 - g);   // g=8->15, 9->14, ..., 15->8
    int p = chunk * 256 + (int)threadIdx.x;
    if (p >= B) return;

    // wave-uniform level parameters (compiler emits s_load / salu)
    float res = (float)resolutions[l];
    unsigned off  = (unsigned)offsets[l];
    unsigned size = (unsigned)offsets[l + 1] - off;
    unsigned mask = size - 1u;
    bool pow2 = (size & mask) == 0u;

    float mn0 = min_xyz[0], mn1 = min_xyz[1], mn2 = min_xyz[2];
    float mx0 = max_xyz[0], mx1 = max_xyz[1], mx2 = max_xyz[2];

    float x = xyz[p * 3 + 0];
    float y = xyz[p * 3 + 1];
    float z = xyz[p * 3 + 2];
    // bit-exact fp32 chain (must match reference op order)
    float ux = (x - mn0) / (mx0 - mn0);
    float uy = (y - mn1) / (mx1 - mn1);
    float uz = (z - mn2) / (mx2 - mn2);
    bool valid = (ux >= 0.0f) & (ux <= 1.0f) &
                 (uy >= 0.0f) & (uy <= 1.0f) &
                 (uz >= 0.0f) & (uz <= 1.0f);

    float rm1 = res - 1.0f;
    float px = ux * res, py = uy * res, pz = uz * res;
    float p0x = fminf(fmaxf(floorf(px), 0.0f), rm1);
    float p0y = fminf(fmaxf(floorf(py), 0.0f), rm1);
    float p0z = fminf(fmaxf(floorf(pz), 0.0f), rm1);
    float fx = px - p0x, fy = py - p0y, fz = pz - p0z;
    float gx = 1.0f - fx, gy = 1.0f - fy, gz = 1.0f - fz;

    unsigned cx0 = (unsigned)p0x;
    unsigned cy0 = (unsigned)p0y;
    unsigned cz0 = (unsigned)p0z;

    const unsigned P1 = 2654435761u;
    const unsigned P2 = 805459861u;

    float o0 = 0.0f, o1 = 0.0f;
#pragma unroll
    for (int c = 0; c < 8; ++c) {
        unsigned bx = (unsigned)(c & 1);
        unsigned by = (unsigned)((c >> 1) & 1);
        unsigned bz = (unsigned)((c >> 2) & 1);
        unsigned h = (cx0 + bx) ^ ((cy0 + by) * P1) ^ ((cz0 + bz) * P2);
        unsigned hm = pow2 ? (h & mask) : (h % size);
        unsigned idx = hm + off;
        float w = (bx ? fx : gx) * (by ? fy : gy);
        w = w * (bz ? fz : gz);
        const float2 e = *reinterpret_cast<const float2*>(emb + (size_t)idx * NFEAT);
        o0 += w * e.x;
        o1 += w * e.y;
    }
    if (!valid) { o0 = 0.0f; o1 = 0.0f; }

    f32x2 result;
    result.x = o0;
    result.y = o1;
    // scattered 8B store: each point's 128B row is filled by 16 blocks
    f32x2* op = reinterpret_cast<f32x2*>(out + (size_t)p * (NLVL * NFEAT) + l * NFEAT);
    __builtin_nontemporal_store(result, op);
}

extern "C" void kernel_launch(void* const* d_in, const int* in_sizes, int n_in,
                              void* d_out, int out_size, void* d_ws, size_t ws_size,
                              hipStream_t stream) {
    const float* xyz        = (const float*)d_in[0];
    const float* embeddings = (const float*)d_in[1];
    const int*   offsets    = (const int*)d_in[2];
    const int*   resolutions= (const int*)d_in[3];
    const float* min_xyz    = (const float*)d_in[4];
    const float* max_xyz    = (const float*)d_in[5];
    float* out = (float*)d_out;

    int B = in_sizes[0] / 3;
    int nchunks = (B + 255) / 256;
    int grid = nchunks * NLVL;
    hashgrid_encode_lvl_kernel<<<grid, 256, 0, stream>>>(
        xyz, embeddings, offsets, resolutions, min_xyz, max_xyz, out, B);
}